// Round 1
// 1007.562 us; speedup vs baseline: 1.1938x; 1.1938x over previous
//
#include <hip/hip_runtime.h>

#define NROWS 8192
#define RPB   64
#define TPB   1024     // 16 waves/block -> forced 4 waves/SIMD co-residency
#define NBLK  128

// workspace layout (float offsets)
#define OFF_W1   0          // 1024
#define OFF_W2   1024       // 1024
#define OFF_WIN  2048       // 102*34 = 3468
#define OFF_WFC2 5516       // 1024
#define OFF_M    6540       // 32*34 = 1088
#define OFF_B12  7628       // 32
#define OFF_BIN  7660       // 102
#define OFF_B2   7762       // 32
#define OFF_BFC2 7794       // 32
#define OFF_LNG  7826       // 32
#define OFF_LNB  7858       // 32
#define OFF_QKV0 8192
#define QKVN     (NROWS*102)          // feature-major: qkv[e][row]
#define OFF_QKV1 (OFF_QKV0 + QKVN)
#define OFF_HNEW (OFF_QKV1 + QKVN)   // feature-major: hnew[j][row], 32*NROWS

__global__ __launch_bounds__(256) void setup_kernel(
    const float* __restrict__ W_x2h, const float* __restrict__ b_x2h,
    const float* __restrict__ W_h2h, const float* __restrict__ b_h2h,
    const float* __restrict__ W_fc2, const float* __restrict__ b_fc2,
    const float* __restrict__ ln_g,  const float* __restrict__ ln_b,
    const float* __restrict__ W_fcsa,const float* __restrict__ b_fcsa,
    const float* __restrict__ W_in,  const float* __restrict__ b_in,
    const float* __restrict__ W_out, const float* __restrict__ b_out,
    float* __restrict__ ws)
{
  int t = blockIdx.x*blockDim.x + threadIdx.x;
  int stride = gridDim.x*blockDim.x;
  for (int i=t;i<1024;i+=stride) ws[OFF_W1+i]   = W_x2h[i];
  for (int i=t;i<1024;i+=stride) ws[OFF_W2+i]   = W_h2h[i];
  for (int i=t;i<3468;i+=stride) ws[OFF_WIN+i]  = W_in[i];
  for (int i=t;i<1024;i+=stride) ws[OFF_WFC2+i] = W_fc2[i];
  for (int i=t;i<32;i+=stride)   ws[OFF_B12+i]  = b_x2h[i] + b_h2h[i];
  for (int i=t;i<102;i+=stride)  ws[OFF_BIN+i]  = b_in[i];
  for (int i=t;i<32;i+=stride)   ws[OFF_BFC2+i] = b_fc2[i];
  for (int i=t;i<32;i+=stride)   ws[OFF_LNG+i]  = ln_g[i];
  for (int i=t;i<32;i+=stride)   ws[OFF_LNB+i]  = ln_b[i];
  // M = W_fcsa (32x34) @ W_out (34x34)
  for (int idx=t; idx<1088; idx+=stride) {
    int j = idx/34, f = idx - j*34;
    float acc = 0.f;
    for (int e=0;e<34;++e)
      acc += W_fcsa[j*34+e] * W_out[e*34+f];
    ws[OFF_M+idx] = acc;
  }
  for (int j=t;j<32;j+=stride){
    float acc = b_fcsa[j];
    for (int e=0;e<34;++e) acc += W_fcsa[j*34+e] * b_out[e];
    ws[OFF_B2+j] = acc;
  }
}

// One launch = attention/update/pred of step stepB + tanh-rnn/qkv of step stepA=stepB+1.
// lane (tid&63) = row; 16 waves = 16 wave-uniform feature slices (wu via
// readfirstlane -> all weight reads stay s_load / scalar-cache).
// 1024-thread block forces 16 waves on one CU = 4 waves/SIMD (vs 2 before),
// halves every phase's per-wave critical path, and the 7 waves idle during
// the scores phase prefetch hnewG into LDS for the h' phase.
__global__ __launch_bounds__(TPB) void step_kernel(
    const float* __restrict__ ws,
    const float* __restrict__ qkvR,     // qkv of step stepB (read)
    float* __restrict__ qkvW,           // qkv of step stepA (write)
    float* __restrict__ hnewG,          // feature-major tanh-state
    const float* __restrict__ x,
    float* __restrict__ out,
    int stepB, int stepA)
{
  const float* W1f   = ws + OFF_W1;
  const float* W2f   = ws + OFF_W2;
  const float* Winf  = ws + OFF_WIN;
  const float* Wfc2f = ws + OFF_WFC2;
  const float* Mf    = ws + OFF_M;
  const float* b12f  = ws + OFF_B12;
  const float* binf  = ws + OFF_BIN;
  const float* b2f   = ws + OFF_B2;
  const float* bfc2f = ws + OFF_BFC2;
  const float* lngf  = ws + OFF_LNG;
  const float* lnbf  = ws + OFF_LNB;

  __shared__ float sS[RPB][13];     // 9 scores (stride 13: conflict-free)
  __shared__ float sO[RPB][35];     // attention output (34)
  __shared__ float sHp[RPB][33];    // h' (post-attention state; prestaged hnew)
  __shared__ float sG[RPB][33];     // pre-LN fc2 output
  __shared__ float sPred[RPB][33];  // pred (next-step input)
  __shared__ float sHn[RPB][33];    // h_new (tanh output)
  __shared__ float sX[RPB][33];     // staged x chunk (steps 0..9)

  const int tid = threadIdx.x;
  const int lr  = tid & 63;
  const int wu  = __builtin_amdgcn_readfirstlane(tid >> 6);  // wave id 0..15, SGPR
  const int base= blockIdx.x * RPB;
  const int r   = base + lr;
  const int b   = r >> 12;
  const int p   = r & 4095;
  const int gr  = p >> 6, gc = p & 63;
  const int br  = (gr < 1) ? 1 : ((gr > 62) ? 62 : gr);
  const int bc  = (gc < 1) ? 1 : ((gc > 62) ? 62 : gc);

  if (stepB >= 0) {
    // ---- phase 1: scores (waves 0..8, m=wu) || hnew prestage (waves 9..15) ----
    if (wu < 9) {
      const int qrow = (b<<12) + (br<<6) + bc;           // query = gathered center
      const int m  = wu;
      const int dr = m/3 - 1, dc = m - (m/3)*3 - 1;
      const int nr_ = (b<<12) + ((br+dr)<<6) + (bc+dc);
      float acc = 0.f;
      #pragma unroll
      for (int e=0;e<34;++e)
        acc += qkvR[(size_t)e*NROWS + qrow] * qkvR[(size_t)(34+e)*NROWS + nr_];
      sS[lr][m] = acc * 0.1714985851425088f;             // 1/sqrt(34)
    } else {
      // prestage hnewG rows into sHp (32 feats x 64 rows = 2048 vals, 448 lanes)
      const int tid2 = (wu-9)*64 + lr;                   // 0..447
      #pragma unroll
      for (int it=0; it<5; ++it) {
        int idx = tid2 + it*448;
        if (idx < 2048) {
          int j = idx >> 6, rr = idx & 63;
          sHp[rr][j] = hnewG[(size_t)j*NROWS + base + rr];
        }
      }
    }
    __syncthreads();
    // ---- phase 2: softmax (redundant per wave, registers) + o slice ----
    {
      float sc[9]; float mx = -1e30f;
      #pragma unroll
      for (int m=0;m<9;++m){ sc[m]=sS[lr][m]; mx=fmaxf(mx,sc[m]); }
      float sum=0.f;
      #pragma unroll
      for (int m=0;m<9;++m){ sc[m]=__expf(sc[m]-mx); sum+=sc[m]; }
      float inv = 1.f/sum;
      float o0=0.f, o1=0.f, o2=0.f;
      const bool e2ok = (wu < 2);                        // wave-uniform
      #pragma unroll
      for (int m=0;m<9;++m){
        int dr = m/3 - 1, dc = m - (m/3)*3 - 1;
        int nr_ = (b<<12) + ((br+dr)<<6) + (bc+dc);
        float wm = sc[m]*inv;
        o0 += wm * qkvR[(size_t)(68+wu)   *NROWS + nr_];
        o1 += wm * qkvR[(size_t)(68+wu+16)*NROWS + nr_];
        if (e2ok) o2 += wm * qkvR[(size_t)(68+wu+32)*NROWS + nr_];
      }
      sO[lr][wu]    = o0;
      sO[lr][wu+16] = o1;
      if (e2ok) sO[lr][wu+32] = o2;
    }
    __syncthreads();
    // ---- phase 3: h' = hnew(prestaged) + o @ M^T + b2 : wave wu -> j = 2wu,2wu+1 ----
    {
      const int j0 = wu*2;
      float a0 = b2f[j0], a1 = b2f[j0+1];
      #pragma unroll
      for (int e=0;e<34;++e){
        float ov = sO[lr][e];
        a0 += ov * Mf[j0*34+e];                          // s_load weights
        a1 += ov * Mf[(j0+1)*34+e];
      }
      sHp[lr][j0]   += a0;
      sHp[lr][j0+1] += a1;
    }
    __syncthreads();
    // ---- phase 4: g = h' @ Wfc2^T + b ----
    {
      const int j0 = wu*2;
      float g0 = bfc2f[j0], g1 = bfc2f[j0+1];
      #pragma unroll
      for (int i=0;i<32;++i){
        float hv = sHp[lr][i];
        g0 += hv * Wfc2f[j0*32+i];                       // s_load
        g1 += hv * Wfc2f[(j0+1)*32+i];
      }
      sG[lr][j0]=g0; sG[lr][j0+1]=g1;
    }
    __syncthreads();
    // ---- phase 5: layernorm -> sPred ----
    {
      float mu=0.f;
      #pragma unroll
      for (int i=0;i<32;++i) mu += sG[lr][i];
      mu *= 0.03125f;
      float var=0.f;
      #pragma unroll
      for (int i=0;i<32;++i){ float d=sG[lr][i]-mu; var += d*d; }
      var *= 0.03125f;
      float rs = rsqrtf(var + 1e-5f);
      const int j0 = wu*2;
      sPred[lr][j0]   = (sG[lr][j0]  -mu)*rs*lngf[j0]   + lnbf[j0];
      sPred[lr][j0+1] = (sG[lr][j0+1]-mu)*rs*lngf[j0+1] + lnbf[j0+1];
    }
    __syncthreads();
    // ---- coalesced out write (block chunk is 2048 contiguous floats) ----
    {
      size_t obase = ((size_t)stepB*NROWS + base)*32;
      #pragma unroll
      for (int it=0; it<2; ++it){
        int idx = tid + it*TPB;
        out[obase + idx] = sPred[idx>>5][idx&31];
      }
    }
  } else {
    // step 0: h' = 0
    const int j0 = wu*2;
    sHp[lr][j0]=0.f; sHp[lr][j0+1]=0.f;
    __syncthreads();
  }

  if (stepA >= 0) {
    // ---- stage x chunk (coalesced) if this step consumes observations ----
    if (stepA < 10) {
      size_t xbase = ((size_t)stepA*NROWS + base)*32;
      #pragma unroll
      for (int it=0; it<2; ++it){
        int idx = tid + it*TPB;
        sX[idx>>5][idx&31] = x[xbase + idx];
      }
    }
    __syncthreads();
    // ---- h_new = tanh(inp@W1^T + h'@W2^T + b) : wave wu -> j = 2wu,2wu+1 ----
    const int j0 = wu*2;
    float a0=b12f[j0], a1=b12f[j0+1];
    if (stepA < 10) {
      #pragma unroll
      for (int i=0;i<32;++i){
        float xv=sX[lr][i], hv=sHp[lr][i];
        a0 += xv*W1f[j0*32+i]     + hv*W2f[j0*32+i];     // s_load
        a1 += xv*W1f[(j0+1)*32+i] + hv*W2f[(j0+1)*32+i];
      }
    } else {
      #pragma unroll
      for (int i=0;i<32;++i){
        float xv=sPred[lr][i], hv=sHp[lr][i];
        a0 += xv*W1f[j0*32+i]     + hv*W2f[j0*32+i];     // s_load
        a1 += xv*W1f[(j0+1)*32+i] + hv*W2f[(j0+1)*32+i];
      }
    }
    {
      float t0 = tanhf(a0), t1 = tanhf(a1);
      sHn[lr][j0]=t0; sHn[lr][j0+1]=t1;
      hnewG[(size_t)j0*NROWS + r]=t0;                    // coalesced (feature-major)
      hnewG[(size_t)(j0+1)*NROWS + r]=t1;
    }
    __syncthreads();
    // ---- qkv = [h_new, pl] @ W_in^T + b_in : wave wu -> e = wu + 16k ----
    float hn[32];
    #pragma unroll
    for (int f=0;f<32;++f) hn[f]=sHn[lr][f];
    const float pl0 = gr*0.015625f, pl1 = gc*0.015625f;
    #pragma unroll
    for (int k=0;k<7;++k){
      int e = wu + 16*k;                                 // wave-uniform
      if (e < 102) {
        float acc = binf[e];
        #pragma unroll
        for (int f=0;f<32;++f) acc += hn[f]*Winf[e*34+f];  // s_load
        acc += pl0*Winf[e*34+32] + pl1*Winf[e*34+33];
        qkvW[(size_t)e*NROWS + r] = acc;                 // coalesced (feature-major)
      }
    }
  }
}

extern "C" void kernel_launch(void* const* d_in, const int* in_sizes, int n_in,
                              void* d_out, int out_size, void* d_ws, size_t ws_size,
                              hipStream_t stream) {
  const float* x     = (const float*)d_in[0];
  const float* W_x2h = (const float*)d_in[1];
  const float* b_x2h = (const float*)d_in[2];
  const float* W_h2h = (const float*)d_in[3];
  const float* b_h2h = (const float*)d_in[4];
  const float* W_fc2 = (const float*)d_in[5];
  const float* b_fc2 = (const float*)d_in[6];
  const float* ln_g  = (const float*)d_in[7];
  const float* ln_b  = (const float*)d_in[8];
  const float* W_fcsa= (const float*)d_in[9];
  const float* b_fcsa= (const float*)d_in[10];
  const float* W_in  = (const float*)d_in[11];
  const float* b_in  = (const float*)d_in[12];
  const float* W_out = (const float*)d_in[13];
  const float* b_out = (const float*)d_in[14];
  float* ws = (float*)d_ws;
  float* out = (float*)d_out;

  setup_kernel<<<8, 256, 0, stream>>>(W_x2h,b_x2h,W_h2h,b_h2h,W_fc2,b_fc2,ln_g,ln_b,
                                      W_fcsa,b_fcsa,W_in,b_in,W_out,b_out, ws);
  for (int i=0;i<60;++i){
    int stepB = i-1;
    int stepA = (i<=58)? i : -1;
    const float* qR = ws + OFF_QKV0 + (size_t)((i+1)&1)*QKVN;  // qkv of step i-1
    float*       qW = ws + OFF_QKV0 + (size_t)(i&1)*QKVN;      // qkv of step i
    step_kernel<<<NBLK, TPB, 0, stream>>>(ws, qR, qW, ws+OFF_HNEW, x, out, stepB, stepA);
  }
}